// Round 4
// baseline (96.456 us; speedup 1.0000x reference)
//
#include <hip/hip_runtime.h>
#include <cstddef>

// Y = P X P, P = I - M, M = blockdiag of 16 (1/8)*ones(8,8).
// Y[i,k] = X[i,k] - rmean[g(i)][k] - cmean[i][h(k)] + bmean[g(i)][h(k)]
// Fully separable into contiguous 8x128 row-slices (4 KiB each).
// One wave per slice; reductions via shfl_xor, no LDS.
// R1: 2-tile unroll + nontemporal (536 MB stream > 256 MB L3).
// R2: ext_vector_type(4) for nontemporal builtins.
// R4: 4-tile unroll — 16 outstanding loads/wave, 16 KiB contiguous per wave
//     per iteration; __launch_bounds__(256,4) caps VGPR at 128 (16 waves/CU).

typedef float v4f __attribute__((ext_vector_type(4)));

__device__ __forceinline__ void process_tile(v4f* __restrict__ dst,
                                             int lane,
                                             v4f x0, v4f x1, v4f x2, v4f x3) {
    // float4 index f = lane + 64*q  ->  row = f>>5 (= p + 2q, p = lane>=32),
    //                                   col-group = lane&31 (cols 4c..4c+3)
    // ---- column sums over all 8 rows (rmean*8) ----
    v4f rs = (x0 + x1) + (x2 + x3);
    rs[0] += __shfl_xor(rs[0], 32);   // add other row-parity (same cols)
    rs[1] += __shfl_xor(rs[1], 32);
    rs[2] += __shfl_xor(rs[2], 32);
    rs[3] += __shfl_xor(rs[3], 32);

    // ---- row sums within this lane's 8-col block (cmean*8) ----
    float c0 = (x0[0] + x0[1]) + (x0[2] + x0[3]);
    float c1 = (x1[0] + x1[1]) + (x1[2] + x1[3]);
    float c2 = (x2[0] + x2[1]) + (x2[2] + x2[3]);
    float c3 = (x3[0] + x3[1]) + (x3[2] + x3[3]);
    c0 += __shfl_xor(c0, 1);          // partner col-group completes the 8-col block
    c1 += __shfl_xor(c1, 1);
    c2 += __shfl_xor(c2, 1);
    c3 += __shfl_xor(c3, 1);

    // ---- 8x8 block sum (bmean*64) ----
    float bs = (rs[0] + rs[1]) + (rs[2] + rs[3]);
    bs += __shfl_xor(bs, 1);

    const float bm = bs * (1.0f / 64.0f);
    const float t0 = bm - c0 * 0.125f;
    const float t1 = bm - c1 * 0.125f;
    const float t2 = bm - c2 * 0.125f;
    const float t3 = bm - c3 * 0.125f;

    v4f rm = rs * 0.125f;

    v4f y0 = (x0 - rm) + t0;
    v4f y1 = (x1 - rm) + t1;
    v4f y2 = (x2 - rm) + t2;
    v4f y3 = (x3 - rm) + t3;

    __builtin_nontemporal_store(y0, &dst[lane]);
    __builtin_nontemporal_store(y1, &dst[lane + 64]);
    __builtin_nontemporal_store(y2, &dst[lane + 128]);
    __builtin_nontemporal_store(y3, &dst[lane + 192]);
}

__global__ __launch_bounds__(256, 4) void pxp_kernel(const float* __restrict__ X,
                                                     float* __restrict__ Y,
                                                     int num_tiles) {
    const int lane  = threadIdx.x & 63;
    const int wave  = (int)((blockIdx.x * blockDim.x + threadIdx.x) >> 6);
    const int nwav  = (int)((gridDim.x * blockDim.x) >> 6);

    // 4 consecutive tiles per iteration: 16 outstanding loads, 16 KiB
    // contiguous read + 16 KiB contiguous write per wave per iteration.
    int t = wave * 4;
    const int stride = nwav * 4;
    for (; t + 3 < num_tiles; t += stride) {
        const v4f* __restrict__ src = reinterpret_cast<const v4f*>(X) + (size_t)t * 256;
        v4f*       __restrict__ dst = reinterpret_cast<v4f*>(Y)       + (size_t)t * 256;

        v4f a0 = __builtin_nontemporal_load(&src[lane]);
        v4f a1 = __builtin_nontemporal_load(&src[lane + 64]);
        v4f a2 = __builtin_nontemporal_load(&src[lane + 128]);
        v4f a3 = __builtin_nontemporal_load(&src[lane + 192]);
        v4f b0 = __builtin_nontemporal_load(&src[lane + 256]);
        v4f b1 = __builtin_nontemporal_load(&src[lane + 320]);
        v4f b2 = __builtin_nontemporal_load(&src[lane + 384]);
        v4f b3 = __builtin_nontemporal_load(&src[lane + 448]);
        v4f c0 = __builtin_nontemporal_load(&src[lane + 512]);
        v4f c1 = __builtin_nontemporal_load(&src[lane + 576]);
        v4f c2 = __builtin_nontemporal_load(&src[lane + 640]);
        v4f c3 = __builtin_nontemporal_load(&src[lane + 704]);
        v4f d0 = __builtin_nontemporal_load(&src[lane + 768]);
        v4f d1 = __builtin_nontemporal_load(&src[lane + 832]);
        v4f d2 = __builtin_nontemporal_load(&src[lane + 896]);
        v4f d3 = __builtin_nontemporal_load(&src[lane + 960]);

        process_tile(dst,       lane, a0, a1, a2, a3);
        process_tile(dst + 256, lane, b0, b1, b2, b3);
        process_tile(dst + 512, lane, c0, c1, c2, c3);
        process_tile(dst + 768, lane, d0, d1, d2, d3);
    }
    // tail (not taken for 65536 tiles / 8192 waves, kept for safety)
    for (; t < num_tiles; ++t) {
        const v4f* __restrict__ src = reinterpret_cast<const v4f*>(X) + (size_t)t * 256;
        v4f*       __restrict__ dst = reinterpret_cast<v4f*>(Y)       + (size_t)t * 256;
        v4f x0 = __builtin_nontemporal_load(&src[lane]);
        v4f x1 = __builtin_nontemporal_load(&src[lane + 64]);
        v4f x2 = __builtin_nontemporal_load(&src[lane + 128]);
        v4f x3 = __builtin_nontemporal_load(&src[lane + 192]);
        process_tile(dst, lane, x0, x1, x2, x3);
    }
}

extern "C" void kernel_launch(void* const* d_in, const int* in_sizes, int n_in,
                              void* d_out, int out_size, void* d_ws, size_t ws_size,
                              hipStream_t stream) {
    const float* X = (const float*)d_in[0];
    // d_in[1] (P) is unused: its block structure (16 centering blocks of 8) is
    // hardcoded analytically, matching reference _build_P().
    float* Y = (float*)d_out;

    const int num_tiles = in_sizes[0] / 1024;          // 8x128 slices (65536)
    const int threads = 256;                           // 4 waves/block
    int blocks = (num_tiles + 7) / 8;
    if (blocks > 2048) blocks = 2048;                  // 8192 waves, 8 tiles/wave

    pxp_kernel<<<blocks, threads, 0, stream>>>(X, Y, num_tiles);
}

// Round 5
// 93.714 us; speedup vs baseline: 1.0293x; 1.0293x over previous
//
#include <hip/hip_runtime.h>
#include <cstddef>

// Y = P X P, P = I - M, M = blockdiag of 16 (1/8)*ones(8,8).
// Y[i,k] = X[i,k] - rmean[g(i)][k] - cmean[i][h(k)] + bmean[g(i)][h(k)]
// Fully separable into contiguous 8x128 row-slices (4 KiB each).
// One wave per slice; reductions via shfl_xor, no LDS.
// R1: 2-tile unroll + nontemporal (536 MB stream > 256 MB L3).
// R2: ext_vector_type(4) for nontemporal builtins.
// R4: 4-tile unroll tried -> -2.5% (MLP already sufficient at 8 loads/wave);
// R5: reverted to the R3 2-tile version (best: 94.08 us, 5.71 TB/s = 91% of
//     the 6.29 TB/s measured D2D copy ceiling). Mixed R/W stream-bound.

typedef float v4f __attribute__((ext_vector_type(4)));

__device__ __forceinline__ void process_tile(v4f* __restrict__ dst,
                                             int lane,
                                             v4f x0, v4f x1, v4f x2, v4f x3) {
    // float4 index f = lane + 64*q  ->  row = f>>5 (= p + 2q, p = lane>=32),
    //                                   col-group = lane&31 (cols 4c..4c+3)
    // ---- column sums over all 8 rows (rmean*8) ----
    v4f rs = (x0 + x1) + (x2 + x3);
    rs[0] += __shfl_xor(rs[0], 32);   // add other row-parity (same cols)
    rs[1] += __shfl_xor(rs[1], 32);
    rs[2] += __shfl_xor(rs[2], 32);
    rs[3] += __shfl_xor(rs[3], 32);

    // ---- row sums within this lane's 8-col block (cmean*8) ----
    float c0 = (x0[0] + x0[1]) + (x0[2] + x0[3]);
    float c1 = (x1[0] + x1[1]) + (x1[2] + x1[3]);
    float c2 = (x2[0] + x2[1]) + (x2[2] + x2[3]);
    float c3 = (x3[0] + x3[1]) + (x3[2] + x3[3]);
    c0 += __shfl_xor(c0, 1);          // partner col-group completes the 8-col block
    c1 += __shfl_xor(c1, 1);
    c2 += __shfl_xor(c2, 1);
    c3 += __shfl_xor(c3, 1);

    // ---- 8x8 block sum (bmean*64) ----
    float bs = (rs[0] + rs[1]) + (rs[2] + rs[3]);
    bs += __shfl_xor(bs, 1);

    const float bm = bs * (1.0f / 64.0f);
    const float t0 = bm - c0 * 0.125f;
    const float t1 = bm - c1 * 0.125f;
    const float t2 = bm - c2 * 0.125f;
    const float t3 = bm - c3 * 0.125f;

    v4f rm = rs * 0.125f;

    v4f y0 = (x0 - rm) + t0;
    v4f y1 = (x1 - rm) + t1;
    v4f y2 = (x2 - rm) + t2;
    v4f y3 = (x3 - rm) + t3;

    __builtin_nontemporal_store(y0, &dst[lane]);
    __builtin_nontemporal_store(y1, &dst[lane + 64]);
    __builtin_nontemporal_store(y2, &dst[lane + 128]);
    __builtin_nontemporal_store(y3, &dst[lane + 192]);
}

__global__ __launch_bounds__(256) void pxp_kernel(const float* __restrict__ X,
                                                  float* __restrict__ Y,
                                                  int num_tiles) {
    const int lane  = threadIdx.x & 63;
    const int wave  = (int)((blockIdx.x * blockDim.x + threadIdx.x) >> 6);
    const int nwav  = (int)((gridDim.x * blockDim.x) >> 6);

    int t = wave * 2;
    const int stride = nwav * 2;
    for (; t + 1 < num_tiles; t += stride) {
        const v4f* __restrict__ srcA = reinterpret_cast<const v4f*>(X) + (size_t)t * 256;
        v4f*       __restrict__ dstA = reinterpret_cast<v4f*>(Y)       + (size_t)t * 256;
        const v4f* __restrict__ srcB = srcA + 256;
        v4f*       __restrict__ dstB = dstA + 256;

        // Issue all 8 loads before any reduction: 8 outstanding vmem ops/wave.
        v4f a0 = __builtin_nontemporal_load(&srcA[lane]);
        v4f a1 = __builtin_nontemporal_load(&srcA[lane + 64]);
        v4f a2 = __builtin_nontemporal_load(&srcA[lane + 128]);
        v4f a3 = __builtin_nontemporal_load(&srcA[lane + 192]);
        v4f b0 = __builtin_nontemporal_load(&srcB[lane]);
        v4f b1 = __builtin_nontemporal_load(&srcB[lane + 64]);
        v4f b2 = __builtin_nontemporal_load(&srcB[lane + 128]);
        v4f b3 = __builtin_nontemporal_load(&srcB[lane + 192]);

        process_tile(dstA, lane, a0, a1, a2, a3);
        process_tile(dstB, lane, b0, b1, b2, b3);
    }
    // tail (not taken for 65536 tiles / 8192 waves, kept for safety)
    for (; t < num_tiles; ++t) {
        const v4f* __restrict__ src = reinterpret_cast<const v4f*>(X) + (size_t)t * 256;
        v4f*       __restrict__ dst = reinterpret_cast<v4f*>(Y)       + (size_t)t * 256;
        v4f x0 = __builtin_nontemporal_load(&src[lane]);
        v4f x1 = __builtin_nontemporal_load(&src[lane + 64]);
        v4f x2 = __builtin_nontemporal_load(&src[lane + 128]);
        v4f x3 = __builtin_nontemporal_load(&src[lane + 192]);
        process_tile(dst, lane, x0, x1, x2, x3);
    }
}

extern "C" void kernel_launch(void* const* d_in, const int* in_sizes, int n_in,
                              void* d_out, int out_size, void* d_ws, size_t ws_size,
                              hipStream_t stream) {
    const float* X = (const float*)d_in[0];
    // d_in[1] (P) is unused: its block structure (16 centering blocks of 8) is
    // hardcoded analytically, matching reference _build_P().
    float* Y = (float*)d_out;

    const int num_tiles = in_sizes[0] / 1024;          // 8x128 slices (65536)
    const int threads = 256;                           // 4 waves/block
    int blocks = (num_tiles + 7) / 8;
    if (blocks > 2048) blocks = 2048;                  // 8192 waves, 8 tiles/wave

    pxp_kernel<<<blocks, threads, 0, stream>>>(X, Y, num_tiles);
}